// Round 9
// baseline (380.998 us; speedup 1.0000x reference)
//
#include <hip/hip_runtime.h>
#include <math.h>

#define Nn 512
#define Ff 64
#define Dd 64
#define Kk 20
#define ROWS 32768
#define EPSc 1e-5f
#define NEG 0.2f
#define NB 512

// ws layout (float units):
//   512     : topk_idx[512*20] (int)
//   10752   : AC1[128] ; 10880: AC2[128]
//   11264   : a_i[32768]
//   44032   : a_j[32768]
//   76800   : xw[32768*64]
//   2173952 : gout/y [32768*64]
//   4271104 : ctr[576] (ints, barrier counters; zeroed via hipMemsetAsync)
//   4271744 : part1[512*128]
//   4337280 : part2[512*128]

__device__ __forceinline__ float dot4(float4 a, float4 b) {
    return a.x*b.x + a.y*b.y + a.z*b.z + a.w*b.w;
}
__device__ __forceinline__ void xr4(float4& a, int m) {
    a.x += __shfl_xor(a.x, m); a.y += __shfl_xor(a.y, m);
    a.z += __shfl_xor(a.z, m); a.w += __shfl_xor(a.w, m);
}

union SMem {
    struct { float wish[64]; float sv[512]; } p1a;                       // topk
    struct { float sh[256]; } p1b;                                       // xw staging
    struct { float a_lds[64][20]; float ssum[4][64]; float ssq[4][64]; } p23;
    struct { float red[2][128]; } pr;                                    // barrier reduce
    struct { float4 s1[4][16]; float4 s2[4][16]; } p5;                   // bn1 stats
    struct { float zsh[4][64]; float hsh[4][32]; } p7;                   // head
};

// ---- hierarchical grid barrier: 8 groups of 64 blocks; device-scope atomics only.
// ctr ints (stride 32 = one 128B line each): grp_cnt[g]=ctr[g*32], root_cnt=ctr[256],
// grp_rel[g]=ctr[288+g*32], root_rel=ctr[544]. Cumulative phase targets (no reset).
__device__ __forceinline__ int gbar_arrive(int* ctr, int phase) {
    __shared__ int s_role;
    int t = threadIdx.x, g = blockIdx.x >> 6;
    __syncthreads();                       // drains this block's stores to L2
    if (t == 0) {
        __threadfence();                   // flush L2 -> device scope
        int a = atomicAdd(&ctr[g*32], 1);
        int r = 0;
        if (a == 64*phase - 1) {           // last of my group
            int b = atomicAdd(&ctr[256], 1);
            r = (b == 8*phase - 1) ? 2 : 1;  // 2 = last overall
        }
        s_role = r;
    }
    __syncthreads();
    return s_role;
}
__device__ __forceinline__ void gbar_wait(int* ctr, int phase, int role) {
    int t = threadIdx.x, g = blockIdx.x >> 6;
    if (t == 0) {
        if (role == 2) { __threadfence(); atomicExch(&ctr[544], phase); }
        if (role >= 1) {
            while (atomicAdd(&ctr[544], 0) < phase) __builtin_amdgcn_s_sleep(2);
            atomicExch(&ctr[288 + g*32], phase);
        } else {
            while (atomicAdd(&ctr[288 + g*32], 0) < phase) __builtin_amdgcn_s_sleep(2);
        }
    }
    __syncthreads();
}

__global__ __launch_bounds__(256, 2) void k_fused(
        const float* __restrict__ data, const float* __restrict__ emb,
        const float* __restrict__ Wg,
        const float* __restrict__ att_i, const float* __restrict__ att_j,
        const float* __restrict__ att_em_i, const float* __restrict__ att_em_j,
        const float* __restrict__ bias,
        const float* __restrict__ bn1_g, const float* __restrict__ bn1_b,
        const float* __restrict__ bn2_g, const float* __restrict__ bn2_b,
        const float* __restrict__ linW, const float* __restrict__ linb,
        const float* __restrict__ outW, const float* __restrict__ outb,
        float* __restrict__ out,
        int* __restrict__ topk, float* __restrict__ ai, float* __restrict__ aj,
        float* __restrict__ xw, float* __restrict__ gout,
        float* __restrict__ AC1, float* __restrict__ AC2,
        float* __restrict__ part1, float* __restrict__ part2,
        int* __restrict__ ctr) {
    __shared__ __align__(16) SMem sm;
    int t = threadIdx.x, blk = blockIdx.x;

    // ===== P1a: topk for row i = blk =====
    {
        int i = blk;
        if (t < 64) {
            float wv = emb[i*64 + t];
            float ss = wv*wv;
            #pragma unroll
            for (int s = 32; s > 0; s >>= 1) ss += __shfl_xor(ss, s);
            sm.p1a.wish[t] = wv * (1.f / sqrtf(ss));
        }
        __syncthreads();
        int seg = t & 3, jl = t >> 2;
        const float4* wish4 = (const float4*)sm.p1a.wish;
        float4 wn[4];
        #pragma unroll
        for (int q = 0; q < 4; q++) wn[q] = wish4[seg*4 + q];
        const float4* emb4 = (const float4*)emb;
        for (int jb = 0; jb < 8; jb++) {
            int j = jb*64 + jl;
            float p = 0.f, s2 = 0.f;
            #pragma unroll
            for (int q = 0; q < 4; q++) {
                float4 e = emb4[j*16 + seg*4 + q];
                p += dot4(e, wn[q]); s2 += dot4(e, e);
            }
            p  += __shfl_xor(p, 1);  p  += __shfl_xor(p, 2);
            s2 += __shfl_xor(s2, 1); s2 += __shfl_xor(s2, 2);
            if (seg == 0) sm.p1a.sv[j] = p * (1.f / sqrtf(s2));
        }
        __syncthreads();
        if (t < 64) {
            float v[8];
            #pragma unroll
            for (int q = 0; q < 8; q++) v[q] = sm.p1a.sv[q*64 + t];
            for (int k = 0; k < Kk; k++) {
                float bv = v[0]; int bi = t;
                #pragma unroll
                for (int q = 1; q < 8; q++)
                    if (v[q] > bv) { bv = v[q]; bi = q*64 + t; }
                #pragma unroll
                for (int s = 1; s < 64; s <<= 1) {
                    float ov = __shfl_xor(bv, s); int oi = __shfl_xor(bi, s);
                    if (ov > bv || (ov == bv && oi < bi)) { bv = ov; bi = oi; }
                }
                if (t == 0) topk[i*Kk + k] = bi;
                #pragma unroll
                for (int q = 0; q < 8; q++)
                    if (bi == q*64 + t) v[q] = -INFINITY;
            }
        }
    }
    __syncthreads();   // union switch p1a -> p1b

    // ===== P1b: xw + a_i/a_j for rows [blk*64, blk*64+64) =====
    {
        float* sh = sm.p1b.sh;
        int d = t & 63, r = t >> 6;
        const float4* wg4 = (const float4*)Wg;
        float4 w4[16];
        #pragma unroll
        for (int q = 0; q < 16; q++) w4[q] = wg4[d*16 + q];
        float atti = att_i[d], attj = att_j[d];
        float aemi = att_em_i[d], aemj = att_em_j[d];
        const float4* sh4 = (const float4*)sh;
        for (int it = 0; it < 16; it++) {
            int g2 = blk*16 + it;
            sh[t] = data[g2*256 + t];     // wave-local LDS (wave r reads own 64)
            float acc = 0.f;
            #pragma unroll
            for (int q = 0; q < 16; q++) acc += dot4(sh4[r*16 + q], w4[q]);
            int row = g2*4 + r;
            xw[row*64 + d] = acc;
            int n = row & (Nn - 1);
            float wv = emb[n*64 + d];
            float vi = acc*atti + wv*aemi;
            float vj = acc*attj + wv*aemj;
            #pragma unroll
            for (int s = 32; s > 0; s >>= 1) { vi += __shfl_xor(vi, s); vj += __shfl_xor(vj, s); }
            if (d == 0) { ai[row] = vi; aj[row] = vj; }
        }
    }

    // ===== B1 =====
    { int role = gbar_arrive(ctr, 1); gbar_wait(ctr, 1, role); }

    // ===== P2: alpha -> LDS (rows blk*64 .. +64), 8 half-waves x 8 iters =====
    {
        int hw = t >> 5, k = t & 31;
        for (int it = 0; it < 8; it++) {
            int lr = it*8 + hw;
            int row = blk*64 + lr;
            int b = row >> 9, n = row & (Nn - 1);
            int base = b << 9;
            float aival = ai[row];
            float v = -1e30f; int j = 0;
            if (k < Kk) {
                j = topk[n*Kk + k];
                float x = aival + aj[base + j];
                v = x > 0.f ? x : NEG * x;
            }
            float m = v;
            #pragma unroll
            for (int s = 1; s <= 16; s <<= 1) m = fmaxf(m, __shfl_xor(m, s));
            float e = (k < Kk) ? __expf(v - m) : 0.f;
            float es = e;
            #pragma unroll
            for (int s = 1; s <= 16; s <<= 1) es += __shfl_xor(es, s);
            if (k < Kk) sm.p23.a_lds[lr][k] = e / es;
        }
    }
    __syncthreads();

    // ===== P3: PV gather + per-block BN1 partials =====
    {
        int d = t & 63, r = t >> 6;
        const int4* topk4 = (const int4*)topk;
        const float4* a4 = (const float4*)&sm.p23.a_lds[0][0];   // row stride 5 f4
        float bias_d = bias[d];
        float lsum = 0.f, lsq = 0.f;
        #pragma unroll 4
        for (int it = 0; it < 16; it++) {
            int lr = it*4 + r;
            int row = blk*64 + lr;
            int n = row & (Nn - 1);
            int base = row & ~(Nn - 1);
            float acc = bias_d;
            #pragma unroll
            for (int c = 0; c < 5; c++) {
                int4   jj = topk4[n*5 + c];
                float4 aa = a4[lr*5 + c];
                acc += aa.x * xw[(base + jj.x)*64 + d];
                acc += aa.y * xw[(base + jj.y)*64 + d];
                acc += aa.z * xw[(base + jj.z)*64 + d];
                acc += aa.w * xw[(base + jj.w)*64 + d];
            }
            gout[row*64 + d] = acc;
            lsum += acc; lsq += acc*acc;
        }
        sm.p23.ssum[r][d] = lsum; sm.p23.ssq[r][d] = lsq;
        __syncthreads();
        if (t < 64) {
            float s1 = sm.p23.ssum[0][t] + sm.p23.ssum[1][t] + sm.p23.ssum[2][t] + sm.p23.ssum[3][t];
            float s2 = sm.p23.ssq[0][t]  + sm.p23.ssq[1][t]  + sm.p23.ssq[2][t]  + sm.p23.ssq[3][t];
            part1[blk*128 + t]      = s1;
            part1[blk*128 + 64 + t] = s2;
        }
    }

    // ===== B2 (+ last block reduces part1 -> AC1) =====
    {
        int role = gbar_arrive(ctr, 2);
        if (role == 2) {
            int ch = t & 127, half = t >> 7;
            float s = 0.f;
            for (int b2 = half; b2 < NB; b2 += 2) s += part1[b2*128 + ch];
            sm.pr.red[half][ch] = s;
            __syncthreads();
            if (t < 64) {
                float ts = sm.pr.red[0][t]      + sm.pr.red[1][t];
                float tq = sm.pr.red[0][64 + t] + sm.pr.red[1][64 + t];
                float mean = ts * (1.f/ROWS);
                float var  = tq * (1.f/ROWS) - mean*mean;
                float A = (1.f / sqrtf(var + EPSc)) * bn1_g[t];
                AC1[t] = A; AC1[64 + t] = bn1_b[t] - mean * A;
            }
            __syncthreads();    // drain AC1 stores; gbar_wait's fence publishes
        }
        gbar_wait(ctr, 2, role);
    }

    // ===== P5: bn1 apply + relu + *emb + BN2 partials (rows blk*64 .. +64) =====
    {
        int q = t & 15;
        float4 A4 = ((const float4*)AC1)[q];
        float4 C4 = ((const float4*)AC1)[16 + q];
        float4 sum4 = {0,0,0,0}, sq4 = {0,0,0,0};
        #pragma unroll
        for (int i = 0; i < 4; i++) {
            int f = blk*1024 + i*256 + t;
            int row = f >> 4, n = row & (Nn - 1);
            float4 x = ((float4*)gout)[f];
            float4 wv = ((const float4*)emb)[n*16 + q];
            float4 v;
            v.x = fmaxf(x.x*A4.x + C4.x, 0.f) * wv.x;
            v.y = fmaxf(x.y*A4.y + C4.y, 0.f) * wv.y;
            v.z = fmaxf(x.z*A4.z + C4.z, 0.f) * wv.z;
            v.w = fmaxf(x.w*A4.w + C4.w, 0.f) * wv.w;
            ((float4*)gout)[f] = v;
            sum4.x += v.x; sum4.y += v.y; sum4.z += v.z; sum4.w += v.w;
            sq4.x += v.x*v.x; sq4.y += v.y*v.y; sq4.z += v.z*v.z; sq4.w += v.w*v.w;
        }
        xr4(sum4, 16); xr4(sum4, 32);
        xr4(sq4, 16);  xr4(sq4, 32);
        int l = t & 63, w = t >> 6;
        __syncthreads();   // union switch p23 -> p5
        if (l < 16) { sm.p5.s1[w][q] = sum4; sm.p5.s2[w][q] = sq4; }
        __syncthreads();
        if (t < 16) {
            float4 a = sm.p5.s1[0][t], c = sm.p5.s2[0][t];
            #pragma unroll
            for (int ww = 1; ww < 4; ww++) {
                float4 x1 = sm.p5.s1[ww][t], x2 = sm.p5.s2[ww][t];
                a.x += x1.x; a.y += x1.y; a.z += x1.z; a.w += x1.w;
                c.x += x2.x; c.y += x2.y; c.z += x2.z; c.w += x2.w;
            }
            ((float4*)part2)[blk*32 + t]      = a;
            ((float4*)part2)[blk*32 + 16 + t] = c;
        }
    }

    // ===== B3 (+ last block reduces part2 -> AC2) =====
    {
        int role = gbar_arrive(ctr, 3);
        if (role == 2) {
            int ch = t & 127, half = t >> 7;
            float s = 0.f;
            for (int b2 = half; b2 < NB; b2 += 2) s += part2[b2*128 + ch];
            sm.pr.red[half][ch] = s;
            __syncthreads();
            if (t < 64) {
                float ts = sm.pr.red[0][t]      + sm.pr.red[1][t];
                float tq = sm.pr.red[0][64 + t] + sm.pr.red[1][64 + t];
                float mean = ts * (1.f/ROWS);
                float var  = tq * (1.f/ROWS) - mean*mean;
                float A = (1.f / sqrtf(var + EPSc)) * bn2_g[t];
                AC2[t] = A; AC2[64 + t] = bn2_b[t] - mean * A;
            }
            __syncthreads();
        }
        gbar_wait(ctr, 3, role);
    }

    // ===== P7: bn2 apply + relu + lin(64->32) + out(32->64), wave-local LDS =====
    {
        int d = t & 63, r = t >> 6;
        int j = d & 31, half = d >> 5;
        float A = AC2[d], C = AC2[64 + d];
        const float4* linW4 = (const float4*)linW;
        const float4* outW4 = (const float4*)outW;
        float4 lw4[8], ow4[8];
        #pragma unroll
        for (int q = 0; q < 8; q++) lw4[q] = linW4[j*16 + half*8 + q];
        #pragma unroll
        for (int q = 0; q < 8; q++) ow4[q] = outW4[d*8 + q];
        float lb = linb[j], ob = outb[d];
        const float4* zsh4 = (const float4*)sm.p7.zsh;
        const float4* hsh4 = (const float4*)sm.p7.hsh;
        for (int it = 0; it < 16; it++) {
            int row = blk*64 + it*4 + r;
            float x = gout[row*64 + d];
            float z = fmaxf(x*A + C, 0.f);
            sm.p7.zsh[r][d] = z;
            float p = 0.f;
            #pragma unroll
            for (int q = 0; q < 8; q++) p += dot4(zsh4[r*16 + half*8 + q], lw4[q]);
            p += __shfl_xor(p, 32);
            if (half == 0) sm.p7.hsh[r][j] = p + lb;
            float o = ob;
            #pragma unroll
            for (int q = 0; q < 8; q++) o += dot4(hsh4[r*8 + q], ow4[q]);
            out[row*64 + d] = o;
        }
    }
}

extern "C" void kernel_launch(void* const* d_in, const int* in_sizes, int n_in,
                              void* d_out, int out_size, void* d_ws, size_t ws_size,
                              hipStream_t stream) {
    const float* data     = (const float*)d_in[0];
    const float* emb      = (const float*)d_in[2];
    const float* Wg       = (const float*)d_in[3];
    const float* att_i    = (const float*)d_in[4];
    const float* att_j    = (const float*)d_in[5];
    const float* att_em_i = (const float*)d_in[6];
    const float* att_em_j = (const float*)d_in[7];
    const float* bias     = (const float*)d_in[8];
    const float* bn1_g    = (const float*)d_in[9];
    const float* bn1_b    = (const float*)d_in[10];
    const float* bn2_g    = (const float*)d_in[11];
    const float* bn2_b    = (const float*)d_in[12];
    const float* linW     = (const float*)d_in[13];
    const float* linb     = (const float*)d_in[14];
    const float* outW     = (const float*)d_in[15];
    const float* outb     = (const float*)d_in[16];
    float* out = (float*)d_out;

    float* ws    = (float*)d_ws;
    int*   topk  = (int*)(ws + 512);
    float* AC1   = ws + 10752;
    float* AC2   = ws + 10880;
    float* a_i   = ws + 11264;
    float* a_j   = ws + 44032;
    float* xw    = ws + 76800;
    float* gout  = ws + 2173952;
    int*   ctr   = (int*)(ws + 4271104);   // 576 ints
    float* part1 = ws + 4271744;
    float* part2 = ws + 4337280;

    hipMemsetAsync(ctr, 0, 576 * sizeof(int), stream);
    k_fused<<<NB, 256, 0, stream>>>(data, emb, Wg, att_i, att_j, att_em_i, att_em_j,
                                    bias, bn1_g, bn1_b, bn2_g, bn2_b,
                                    linW, linb, outW, outb, out,
                                    topk, a_i, a_j, xw, gout,
                                    AC1, AC2, part1, part2, ctr);
}

// Round 10
// 233.543 us; speedup vs baseline: 1.6314x; 1.6314x over previous
//
#include <hip/hip_runtime.h>
#include <math.h>

#define Nn 512
#define Ff 64
#define Dd 64
#define Kk 20
#define ROWS 32768
#define EPSc 1e-5f
#define NEG 0.2f
#define NB 512

// ws layout (float units):
//   512     : topk_idx[512*20] (int)
//   10752   : AC1[128] ; 10880: AC2[128]
//   11264   : a_i[32768]
//   44032   : a_j[32768]
//   76800   : xw[32768*64]
//   2173952 : gout/y [32768*64]
//   4271104 : ctr[64] (ints; ctr[0], ctr[32] used; zeroed via hipMemsetAsync)
//   4271744 : part1[512*128]
//   4337280 : part2[512*128]

__device__ __forceinline__ float dot4(float4 a, float4 b) {
    return a.x*b.x + a.y*b.y + a.z*b.z + a.w*b.w;
}
__device__ __forceinline__ void xr4(float4& a, int m) {
    a.x += __shfl_xor(a.x, m); a.y += __shfl_xor(a.y, m);
    a.z += __shfl_xor(a.z, m); a.w += __shfl_xor(a.w, m);
}

union SMemPV {
    struct { float a_lds[64][20]; float ssum[4][64]; float ssq[4][64]; } p;
    struct { float4 red[8][32]; } pr;
};
union SMemBN {
    struct { float4 s1[4][16]; float4 s2[4][16]; } p;
    struct { float4 red[8][32]; } pr;
};

// last-block tail reduce: partials[NB][128] -> AC[128] = {A[64], C[64]}
template <typename SM>
__device__ __forceinline__ void tail_reduce(const float* __restrict__ part,
                                            const float* __restrict__ g,
                                            const float* __restrict__ bta,
                                            float* __restrict__ AC, SM& sm) {
    int t = threadIdx.x;
    int ch4 = t & 31, h = t >> 5;
    const float4* p4 = (const float4*)part;
    float4 s = {0,0,0,0};
    for (int b = h; b < NB; b += 8) {
        float4 v = p4[b*32 + ch4];
        s.x += v.x; s.y += v.y; s.z += v.z; s.w += v.w;
    }
    sm.pr.red[h][ch4] = s;
    __syncthreads();
    if (t < 32) {
        float4 a = sm.pr.red[0][t];
        #pragma unroll
        for (int i = 1; i < 8; i++) {
            float4 v = sm.pr.red[i][t];
            a.x += v.x; a.y += v.y; a.z += v.z; a.w += v.w;
        }
        sm.pr.red[0][t] = a;    // [0][0..15]=sum4, [0][16..31]=sq4
    }
    __syncthreads();
    if (t < 16) {
        float4 s4 = sm.pr.red[0][t], q4 = sm.pr.red[0][16 + t];
        float4 A4, C4;
        const float* sp = &s4.x; const float* qp = &q4.x;
        float* Ap = &A4.x; float* Cp = &C4.x;
        #pragma unroll
        for (int c = 0; c < 4; c++) {
            int d = 4*t + c;
            float mean = sp[c] * (1.f/ROWS);
            float var  = qp[c] * (1.f/ROWS) - mean*mean;
            float A = (1.f / sqrtf(var + EPSc)) * g[d];
            Ap[c] = A; Cp[c] = bta[d] - mean * A;
        }
        ((float4*)AC)[t]      = A4;
        ((float4*)AC)[16 + t] = C4;
    }
}

// ---------- L1: topk (blocks 0..511) || xw + a_i/a_j (blocks 512..1023)
__global__ __launch_bounds__(256) void k_p1(const float* __restrict__ data,
                                            const float* __restrict__ emb,
                                            const float* __restrict__ Wg,
                                            const float* __restrict__ att_i,
                                            const float* __restrict__ att_j,
                                            const float* __restrict__ att_em_i,
                                            const float* __restrict__ att_em_j,
                                            int* __restrict__ topk,
                                            float* __restrict__ ai,
                                            float* __restrict__ aj,
                                            float* __restrict__ xw) {
    __shared__ __align__(16) float shbuf[576];
    int t = threadIdx.x, blk = blockIdx.x;
    if (blk < Nn) {
        float* wish = shbuf;
        float* sv   = shbuf + 64;
        int i = blk;
        if (t < 64) {
            float wv = emb[i*64 + t];
            float ss = wv*wv;
            #pragma unroll
            for (int s = 32; s > 0; s >>= 1) ss += __shfl_xor(ss, s);
            wish[t] = wv * (1.f / sqrtf(ss));
        }
        __syncthreads();
        int seg = t & 3, jl = t >> 2;
        const float4* wish4 = (const float4*)wish;
        float4 wn[4];
        #pragma unroll
        for (int q = 0; q < 4; q++) wn[q] = wish4[seg*4 + q];
        const float4* emb4 = (const float4*)emb;
        for (int jb = 0; jb < 8; jb++) {
            int j = jb*64 + jl;
            float p = 0.f, s2 = 0.f;
            #pragma unroll
            for (int q = 0; q < 4; q++) {
                float4 e = emb4[j*16 + seg*4 + q];
                p += dot4(e, wn[q]); s2 += dot4(e, e);
            }
            p  += __shfl_xor(p, 1);  p  += __shfl_xor(p, 2);
            s2 += __shfl_xor(s2, 1); s2 += __shfl_xor(s2, 2);
            if (seg == 0) sv[j] = p * (1.f / sqrtf(s2));
        }
        __syncthreads();
        if (t < 64) {
            float v[8];
            #pragma unroll
            for (int q = 0; q < 8; q++) v[q] = sv[q*64 + t];
            for (int k = 0; k < Kk; k++) {
                float bv = v[0]; int bi = t;
                #pragma unroll
                for (int q = 1; q < 8; q++)
                    if (v[q] > bv) { bv = v[q]; bi = q*64 + t; }
                #pragma unroll
                for (int s = 1; s < 64; s <<= 1) {
                    float ov = __shfl_xor(bv, s); int oi = __shfl_xor(bi, s);
                    if (ov > bv || (ov == bv && oi < bi)) { bv = ov; bi = oi; }
                }
                if (t == 0) topk[i*Kk + k] = bi;
                #pragma unroll
                for (int q = 0; q < 8; q++)
                    if (bi == q*64 + t) v[q] = -INFINITY;
            }
        }
    } else {
        float* sh = shbuf;
        int d = t & 63, r = t >> 6;
        const float4* wg4 = (const float4*)Wg;
        float4 w4[16];
        #pragma unroll
        for (int q = 0; q < 16; q++) w4[q] = wg4[d*16 + q];
        float atti = att_i[d], attj = att_j[d];
        float aemi = att_em_i[d], aemj = att_em_j[d];
        const float4* sh4 = (const float4*)sh;
        for (int it = 0; it < 16; it++) {
            int g = (blk - Nn)*16 + it;
            sh[t] = data[g*256 + t];      // wave-local LDS (wave r reads own 64)
            float acc = 0.f;
            #pragma unroll
            for (int q = 0; q < 16; q++) acc += dot4(sh4[r*16 + q], w4[q]);
            int row = g*4 + r;
            xw[row*64 + d] = acc;
            int n = row & (Nn - 1);
            float wv = emb[n*64 + d];
            float vi = acc*atti + wv*aemi;
            float vj = acc*attj + wv*aemj;
            #pragma unroll
            for (int s = 32; s > 0; s >>= 1) { vi += __shfl_xor(vi, s); vj += __shfl_xor(vj, s); }
            if (d == 0) { ai[row] = vi; aj[row] = vj; }
        }
    }
}

// ---------- L2: alpha (LDS) + PV gather + BN1 partials + last-block reduce -> AC1
__global__ __launch_bounds__(256) void k_pv2(const float* __restrict__ xw,
                                             const float* __restrict__ ai,
                                             const float* __restrict__ aj,
                                             const int* __restrict__ topk,
                                             const float* __restrict__ bias,
                                             const float* __restrict__ bn1_g,
                                             const float* __restrict__ bn1_b,
                                             float* __restrict__ gout,
                                             float* __restrict__ part1,
                                             float* __restrict__ AC1,
                                             int* __restrict__ ctr) {
    __shared__ __align__(16) SMemPV sm;
    __shared__ int s_last;
    int t = threadIdx.x, blk = blockIdx.x;

    // alpha for rows [blk*64, blk*64+64) -> LDS
    {
        int hw = t >> 5, k = t & 31;
        for (int it = 0; it < 8; it++) {
            int lr = it*8 + hw;
            int row = blk*64 + lr;
            int n = row & (Nn - 1);
            int base = row & ~(Nn - 1);
            float aival = ai[row];
            float v = -1e30f;
            if (k < Kk) {
                int j = topk[n*Kk + k];
                float x = aival + aj[base + j];
                v = x > 0.f ? x : NEG * x;
            }
            float m = v;
            #pragma unroll
            for (int s = 1; s <= 16; s <<= 1) m = fmaxf(m, __shfl_xor(m, s));
            float e = (k < Kk) ? __expf(v - m) : 0.f;
            float es = e;
            #pragma unroll
            for (int s = 1; s <= 16; s <<= 1) es += __shfl_xor(es, s);
            if (k < Kk) sm.p.a_lds[lr][k] = e / es;
        }
    }
    __syncthreads();

    // PV gather + per-block partials
    {
        int d = t & 63, r = t >> 6;
        const int4* topk4 = (const int4*)topk;
        const float4* a4 = (const float4*)&sm.p.a_lds[0][0];   // row stride 5 f4
        float bias_d = bias[d];
        float lsum = 0.f, lsq = 0.f;
        #pragma unroll 4
        for (int it = 0; it < 16; it++) {
            int lr = it*4 + r;
            int row = blk*64 + lr;
            int n = row & (Nn - 1);
            int base = row & ~(Nn - 1);
            float acc = bias_d;
            #pragma unroll
            for (int c = 0; c < 5; c++) {
                int4   jj = topk4[n*5 + c];
                float4 aa = a4[lr*5 + c];
                acc += aa.x * xw[(base + jj.x)*64 + d];
                acc += aa.y * xw[(base + jj.y)*64 + d];
                acc += aa.z * xw[(base + jj.z)*64 + d];
                acc += aa.w * xw[(base + jj.w)*64 + d];
            }
            gout[row*64 + d] = acc;
            lsum += acc; lsq += acc*acc;
        }
        sm.p.ssum[r][d] = lsum; sm.p.ssq[r][d] = lsq;
        __syncthreads();
        if (t < 64) {
            float s1 = sm.p.ssum[0][t] + sm.p.ssum[1][t] + sm.p.ssum[2][t] + sm.p.ssum[3][t];
            float s2 = sm.p.ssq[0][t]  + sm.p.ssq[1][t]  + sm.p.ssq[2][t]  + sm.p.ssq[3][t];
            part1[blk*128 + t]      = s1;
            part1[blk*128 + 64 + t] = s2;
        }
    }
    __syncthreads();
    if (t == 0) {
        __threadfence();                              // publish partials
        s_last = (atomicAdd(ctr, 1) == NB - 1);
    }
    __syncthreads();                                  // broadcast + union switch
    if (s_last) {
        __threadfence();
        tail_reduce(part1, bn1_g, bn1_b, AC1, sm);    // only last block; no waiting
    }
}

// ---------- L3: bn1 apply + relu + *emb + BN2 partials + last-block reduce -> AC2
__global__ __launch_bounds__(256) void k_bn2(float* __restrict__ gout,
                                             const float* __restrict__ emb,
                                             const float* __restrict__ AC1,
                                             const float* __restrict__ bn2_g,
                                             const float* __restrict__ bn2_b,
                                             float* __restrict__ part2,
                                             float* __restrict__ AC2,
                                             int* __restrict__ ctr) {
    __shared__ __align__(16) SMemBN sm;
    __shared__ int s_last;
    int t = threadIdx.x, blk = blockIdx.x, q = t & 15;
    float4 A4 = ((const float4*)AC1)[q];
    float4 C4 = ((const float4*)AC1)[16 + q];
    float4 sum4 = {0,0,0,0}, sq4 = {0,0,0,0};
    #pragma unroll
    for (int i = 0; i < 4; i++) {
        int f = blk*1024 + i*256 + t;
        int row = f >> 4, n = row & (Nn - 1);
        float4 x = ((float4*)gout)[f];
        float4 wv = ((const float4*)emb)[n*16 + q];
        float4 v;
        v.x = fmaxf(x.x*A4.x + C4.x, 0.f) * wv.x;
        v.y = fmaxf(x.y*A4.y + C4.y, 0.f) * wv.y;
        v.z = fmaxf(x.z*A4.z + C4.z, 0.f) * wv.z;
        v.w = fmaxf(x.w*A4.w + C4.w, 0.f) * wv.w;
        ((float4*)gout)[f] = v;
        sum4.x += v.x; sum4.y += v.y; sum4.z += v.z; sum4.w += v.w;
        sq4.x += v.x*v.x; sq4.y += v.y*v.y; sq4.z += v.z*v.z; sq4.w += v.w*v.w;
    }
    xr4(sum4, 16); xr4(sum4, 32);
    xr4(sq4, 16);  xr4(sq4, 32);
    int l = t & 63, w = t >> 6;
    if (l < 16) { sm.p.s1[w][q] = sum4; sm.p.s2[w][q] = sq4; }
    __syncthreads();
    if (t < 16) {
        float4 a = sm.p.s1[0][t], c = sm.p.s2[0][t];
        #pragma unroll
        for (int ww = 1; ww < 4; ww++) {
            float4 x1 = sm.p.s1[ww][t], x2 = sm.p.s2[ww][t];
            a.x += x1.x; a.y += x1.y; a.z += x1.z; a.w += x1.w;
            c.x += x2.x; c.y += x2.y; c.z += x2.z; c.w += x2.w;
        }
        ((float4*)part2)[blk*32 + t]      = a;
        ((float4*)part2)[blk*32 + 16 + t] = c;
    }
    __syncthreads();
    if (t == 0) {
        __threadfence();
        s_last = (atomicAdd(ctr, 1) == NB - 1);
    }
    __syncthreads();
    if (s_last) {
        __threadfence();
        tail_reduce(part2, bn2_g, bn2_b, AC2, sm);
    }
}

// ---------- L4: bn2 apply + relu + lin(64->32) + out(32->64), wave-local LDS
__global__ __launch_bounds__(256) void k_head3(const float* __restrict__ y,
                                               const float* __restrict__ AC2,
                                               const float* __restrict__ linW,
                                               const float* __restrict__ linb,
                                               const float* __restrict__ outW,
                                               const float* __restrict__ outb,
                                               float* __restrict__ out) {
    __shared__ __align__(16) float zsh[4][64];
    __shared__ __align__(16) float hsh[4][32];
    int t = threadIdx.x;
    int d = t & 63, r = t >> 6;
    int j = d & 31, half = d >> 5;
    float A = AC2[d], C = AC2[64 + d];
    const float4* linW4 = (const float4*)linW;
    const float4* outW4 = (const float4*)outW;
    float4 lw4[8], ow4[8];
    #pragma unroll
    for (int q = 0; q < 8; q++) lw4[q] = linW4[j*16 + half*8 + q];
    #pragma unroll
    for (int q = 0; q < 8; q++) ow4[q] = outW4[d*8 + q];
    float lb = linb[j], ob = outb[d];
    const float4* zsh4 = (const float4*)zsh;
    const float4* hsh4 = (const float4*)hsh;
    for (int it = 0; it < 16; it++) {
        int row = blockIdx.x*64 + it*4 + r;
        float x = y[row*64 + d];
        float z = fmaxf(x*A + C, 0.f);
        zsh[r][d] = z;        // wave-local LDS — no barriers needed
        float p = 0.f;
        #pragma unroll
        for (int q = 0; q < 8; q++) p += dot4(zsh4[r*16 + half*8 + q], lw4[q]);
        p += __shfl_xor(p, 32);
        if (half == 0) hsh[r][j] = p + lb;
        float o = ob;
        #pragma unroll
        for (int q = 0; q < 8; q++) o += dot4(hsh4[r*8 + q], ow4[q]);
        out[row*64 + d] = o;
    }
}

extern "C" void kernel_launch(void* const* d_in, const int* in_sizes, int n_in,
                              void* d_out, int out_size, void* d_ws, size_t ws_size,
                              hipStream_t stream) {
    const float* data     = (const float*)d_in[0];
    const float* emb      = (const float*)d_in[2];
    const float* Wg       = (const float*)d_in[3];
    const float* att_i    = (const float*)d_in[4];
    const float* att_j    = (const float*)d_in[5];
    const float* att_em_i = (const float*)d_in[6];
    const float* att_em_j = (const float*)d_in[7];
    const float* bias     = (const float*)d_in[8];
    const float* bn1_g    = (const float*)d_in[9];
    const float* bn1_b    = (const float*)d_in[10];
    const float* bn2_g    = (const float*)d_in[11];
    const float* bn2_b    = (const float*)d_in[12];
    const float* linW     = (const float*)d_in[13];
    const float* linb     = (const float*)d_in[14];
    const float* outW     = (const float*)d_in[15];
    const float* outb     = (const float*)d_in[16];
    float* out = (float*)d_out;

    float* ws    = (float*)d_ws;
    int*   topk  = (int*)(ws + 512);
    float* AC1   = ws + 10752;
    float* AC2   = ws + 10880;
    float* a_i   = ws + 11264;
    float* a_j   = ws + 44032;
    float* xw    = ws + 76800;
    float* gout  = ws + 2173952;
    int*   ctr   = (int*)(ws + 4271104);   // ctr[0], ctr[32]
    float* part1 = ws + 4271744;
    float* part2 = ws + 4337280;

    hipMemsetAsync(ctr, 0, 64 * sizeof(int), stream);
    k_p1   <<<1024, 256, 0, stream>>>(data, emb, Wg, att_i, att_j, att_em_i, att_em_j,
                                      topk, a_i, a_j, xw);
    k_pv2  <<<NB, 256, 0, stream>>>(xw, a_i, a_j, topk, bias, bn1_g, bn1_b,
                                    gout, part1, AC1, ctr);
    k_bn2  <<<NB, 256, 0, stream>>>(gout, emb, AC1, bn2_g, bn2_b,
                                    part2, AC2, ctr + 32);
    k_head3<<<NB, 256, 0, stream>>>(gout, AC2, linW, linb, outW, outb, out);
}

// Round 13
// 226.209 us; speedup vs baseline: 1.6843x; 1.0324x over previous
//
#include <hip/hip_runtime.h>
#include <math.h>

#define Nn 512
#define Ff 64
#define Dd 64
#define Kk 20
#define ROWS 32768
#define EPSc 1e-5f
#define NEG 0.2f
#define NB 512

// ws layout (float units):
//   512     : topk_idx[512*20] (int)
//   10752   : AC1[128] ; 10880: AC2[128]
//   11264   : a_i[32768]
//   44032   : a_j[32768]
//   76800   : xw[32768*64]
//   2173952 : gout/y [32768*64]
//   4271104 : ctr[64] (ints; ctr[0], ctr[32]; zeroed via hipMemsetAsync)
//   4271744 : part1[512*128]
//   4337280 : part2[512*128]

__device__ __forceinline__ float dot4(float4 a, float4 b) {
    return a.x*b.x + a.y*b.y + a.z*b.z + a.w*b.w;
}
__device__ __forceinline__ void xr4(float4& a, int m) {
    a.x += __shfl_xor(a.x, m); a.y += __shfl_xor(a.y, m);
    a.z += __shfl_xor(a.z, m); a.w += __shfl_xor(a.w, m);
}
// XCD-aligned 64-row tile: all 8 blocks of one batch share blk&7 (same XCD's L2).
__device__ __forceinline__ int xcd_row0(int bb) {
    int xcd = bb & 7, i = bb >> 3;
    int batch = xcd*8 + (i & 7);
    return batch*512 + (i >> 3)*64;
}

union SMemPV {
    struct { float a_lds[64][20]; float ssum[4][64]; float ssq[4][64]; } p;
    struct { float4 red[8][32]; } pr;
};
union SMemBN {
    struct { float4 s1[4][16]; float4 s2[4][16]; } p;
    struct { float4 red[8][32]; } pr;
};

// last-block tail reduce: partials[NB][128] -> AC[128] = {A[64], C[64]}
template <typename SM>
__device__ __forceinline__ void tail_reduce(const float* __restrict__ part,
                                            const float* __restrict__ g,
                                            const float* __restrict__ bta,
                                            float* __restrict__ AC, SM& sm) {
    int t = threadIdx.x;
    int ch4 = t & 31, h = t >> 5;
    const float4* p4 = (const float4*)part;
    float4 s = {0,0,0,0};
    for (int b = h; b < NB; b += 8) {
        float4 v = p4[b*32 + ch4];
        s.x += v.x; s.y += v.y; s.z += v.z; s.w += v.w;
    }
    sm.pr.red[h][ch4] = s;
    __syncthreads();
    if (t < 32) {
        float4 a = sm.pr.red[0][t];
        #pragma unroll
        for (int i = 1; i < 8; i++) {
            float4 v = sm.pr.red[i][t];
            a.x += v.x; a.y += v.y; a.z += v.z; a.w += v.w;
        }
        sm.pr.red[0][t] = a;
    }
    __syncthreads();
    if (t < 16) {
        float4 s4 = sm.pr.red[0][t], q4 = sm.pr.red[0][16 + t];
        float4 A4, C4;
        const float* sp = &s4.x; const float* qp = &q4.x;
        float* Ap = &A4.x; float* Cp = &C4.x;
        #pragma unroll
        for (int c = 0; c < 4; c++) {
            int d = 4*t + c;
            float mean = sp[c] * (1.f/ROWS);
            float var  = qp[c] * (1.f/ROWS) - mean*mean;
            float A = (1.f / sqrtf(var + EPSc)) * g[d];
            Ap[c] = A; Cp[c] = bta[d] - mean * A;
        }
        ((float4*)AC)[t]      = A4;
        ((float4*)AC)[16 + t] = C4;
    }
}

// ---------- L1: topk (blocks 0..511) || xw + a_i/a_j (blocks 512..1023, XCD-aligned)
__global__ __launch_bounds__(256) void k_p1(const float* __restrict__ data,
                                            const float* __restrict__ emb,
                                            const float* __restrict__ Wg,
                                            const float* __restrict__ att_i,
                                            const float* __restrict__ att_j,
                                            const float* __restrict__ att_em_i,
                                            const float* __restrict__ att_em_j,
                                            int* __restrict__ topk,
                                            float* __restrict__ ai,
                                            float* __restrict__ aj,
                                            float* __restrict__ xw) {
    __shared__ __align__(16) float shbuf[576];
    int t = threadIdx.x, blk = blockIdx.x;
    if (blk < Nn) {
        float* wish = shbuf;
        float* sv   = shbuf + 64;
        int i = blk;
        if (t < 64) {
            float wv = emb[i*64 + t];
            float ss = wv*wv;
            #pragma unroll
            for (int s = 32; s > 0; s >>= 1) ss += __shfl_xor(ss, s);
            wish[t] = wv * (1.f / sqrtf(ss));
        }
        __syncthreads();
        int seg = t & 3, jl = t >> 2;
        const float4* wish4 = (const float4*)wish;
        float4 wn[4];
        #pragma unroll
        for (int q = 0; q < 4; q++) wn[q] = wish4[seg*4 + q];
        const float4* emb4 = (const float4*)emb;
        for (int jb = 0; jb < 8; jb++) {
            int j = jb*64 + jl;
            float p = 0.f, s2 = 0.f;
            #pragma unroll
            for (int q = 0; q < 4; q++) {
                float4 e = emb4[j*16 + seg*4 + q];
                p += dot4(e, wn[q]); s2 += dot4(e, e);
            }
            p  += __shfl_xor(p, 1);  p  += __shfl_xor(p, 2);
            s2 += __shfl_xor(s2, 1); s2 += __shfl_xor(s2, 2);
            if (seg == 0) sv[j] = p * (1.f / sqrtf(s2));
        }
        __syncthreads();
        if (t < 64) {
            float v[8];
            #pragma unroll
            for (int q = 0; q < 8; q++) v[q] = sv[q*64 + t];
            for (int k = 0; k < Kk; k++) {
                float bv = v[0]; int bi = t;
                #pragma unroll
                for (int q = 1; q < 8; q++)
                    if (v[q] > bv) { bv = v[q]; bi = q*64 + t; }
                #pragma unroll
                for (int s = 1; s < 64; s <<= 1) {
                    float ov = __shfl_xor(bv, s); int oi = __shfl_xor(bi, s);
                    if (ov > bv || (ov == bv && oi < bi)) { bv = ov; bi = oi; }
                }
                if (t == 0) topk[i*Kk + k] = bi;
                #pragma unroll
                for (int q = 0; q < 8; q++)
                    if (bi == q*64 + t) v[q] = -INFINITY;
            }
        }
    } else {
        float* sh = shbuf;
        int d = t & 63, r = t >> 6;
        const float4* wg4 = (const float4*)Wg;
        float4 w4[16];
        #pragma unroll
        for (int q = 0; q < 16; q++) w4[q] = wg4[d*16 + q];
        float atti = att_i[d], attj = att_j[d];
        float aemi = att_em_i[d], aemj = att_em_j[d];
        const float4* sh4 = (const float4*)sh;
        int row0 = xcd_row0(blk - Nn);              // XCD-aligned 64-row tile
        for (int it = 0; it < 16; it++) {
            int g = (row0 >> 2) + it;
            sh[t] = data[g*256 + t];                // wave-local LDS
            float acc = 0.f;
            #pragma unroll
            for (int q = 0; q < 16; q++) acc += dot4(sh4[r*16 + q], w4[q]);
            int row = g*4 + r;
            xw[row*64 + d] = acc;
            int n = row & (Nn - 1);
            float wv = emb[n*64 + d];
            float vi = acc*atti + wv*aemi;
            float vj = acc*attj + wv*aemj;
            #pragma unroll
            for (int s = 32; s > 0; s >>= 1) { vi += __shfl_xor(vi, s); vj += __shfl_xor(vj, s); }
            if (d == 0) { ai[row] = vi; aj[row] = vj; }
        }
    }
}

// ---------- L2: alpha (LDS) + PV gather + BN1 partials + last-block reduce -> AC1
__global__ __launch_bounds__(256) void k_pv2(const float* __restrict__ xw,
                                             const float* __restrict__ ai,
                                             const float* __restrict__ aj,
                                             const int* __restrict__ topk,
                                             const float* __restrict__ bias,
                                             const float* __restrict__ bn1_g,
                                             const float* __restrict__ bn1_b,
                                             float* __restrict__ gout,
                                             float* __restrict__ part1,
                                             float* __restrict__ AC1,
                                             int* __restrict__ ctr) {
    __shared__ __align__(16) SMemPV sm;
    __shared__ int s_last;
    int t = threadIdx.x, blk = blockIdx.x;
    int row0 = xcd_row0(blk);                       // same mapping as producer

    // alpha for rows [row0, row0+64) -> LDS
    {
        int hw = t >> 5, k = t & 31;
        for (int it = 0; it < 8; it++) {
            int lr = it*8 + hw;
            int row = row0 + lr;
            int n = row & (Nn - 1);
            int base = row & ~(Nn - 1);
            float aival = ai[row];
            float v = -1e30f;
            if (k < Kk) {
                int j = topk[n*Kk + k];
                float x = aival + aj[base + j];
                v = x > 0.f ? x : NEG * x;
            }
            float m = v;
            #pragma unroll
            for (int s = 1; s <= 16; s <<= 1) m = fmaxf(m, __shfl_xor(m, s));
            float e = (k < Kk) ? __expf(v - m) : 0.f;
            float es = e;
            #pragma unroll
            for (int s = 1; s <= 16; s <<= 1) es += __shfl_xor(es, s);
            if (k < Kk) sm.p.a_lds[lr][k] = e / es;
        }
    }
    __syncthreads();

    // PV gather + per-block partials
    {
        int d = t & 63, r = t >> 6;
        const int4* topk4 = (const int4*)topk;
        const float4* a4 = (const float4*)&sm.p.a_lds[0][0];
        float bias_d = bias[d];
        float lsum = 0.f, lsq = 0.f;
        #pragma unroll 4
        for (int it = 0; it < 16; it++) {
            int lr = it*4 + r;
            int row = row0 + lr;
            int n = row & (Nn - 1);
            int base = row & ~(Nn - 1);
            float acc = bias_d;
            #pragma unroll
            for (int c = 0; c < 5; c++) {
                int4   jj = topk4[n*5 + c];
                float4 aa = a4[lr*5 + c];
                acc += aa.x * xw[(base + jj.x)*64 + d];
                acc += aa.y * xw[(base + jj.y)*64 + d];
                acc += aa.z * xw[(base + jj.z)*64 + d];
                acc += aa.w * xw[(base + jj.w)*64 + d];
            }
            gout[row*64 + d] = acc;
            lsum += acc; lsq += acc*acc;
        }
        sm.p.ssum[r][d] = lsum; sm.p.ssq[r][d] = lsq;
        __syncthreads();
        if (t < 64) {
            float s1 = sm.p.ssum[0][t] + sm.p.ssum[1][t] + sm.p.ssum[2][t] + sm.p.ssum[3][t];
            float s2 = sm.p.ssq[0][t]  + sm.p.ssq[1][t]  + sm.p.ssq[2][t]  + sm.p.ssq[3][t];
            part1[blk*128 + t]      = s1;
            part1[blk*128 + 64 + t] = s2;
        }
    }
    __syncthreads();
    if (t == 0) {
        __threadfence();
        s_last = (atomicAdd(ctr, 1) == NB - 1);
    }
    __syncthreads();
    if (s_last) {
        __threadfence();
        tail_reduce(part1, bn1_g, bn1_b, AC1, sm);
    }
}

// ---------- L3: bn1 apply + relu + *emb + BN2 partials + last-block reduce -> AC2
__global__ __launch_bounds__(256) void k_bn2(float* __restrict__ gout,
                                             const float* __restrict__ emb,
                                             const float* __restrict__ AC1,
                                             const float* __restrict__ bn2_g,
                                             const float* __restrict__ bn2_b,
                                             float* __restrict__ part2,
                                             float* __restrict__ AC2,
                                             int* __restrict__ ctr) {
    __shared__ __align__(16) SMemBN sm;
    __shared__ int s_last;
    int t = threadIdx.x, blk = blockIdx.x, q = t & 15;
    float4 A4 = ((const float4*)AC1)[q];
    float4 C4 = ((const float4*)AC1)[16 + q];
    float4 sum4 = {0,0,0,0}, sq4 = {0,0,0,0};
    #pragma unroll
    for (int i = 0; i < 4; i++) {
        int f = blk*1024 + i*256 + t;
        int row = f >> 4, n = row & (Nn - 1);
        float4 x = ((float4*)gout)[f];
        float4 wv = ((const float4*)emb)[n*16 + q];
        float4 v;
        v.x = fmaxf(x.x*A4.x + C4.x, 0.f) * wv.x;
        v.y = fmaxf(x.y*A4.y + C4.y, 0.f) * wv.y;
        v.z = fmaxf(x.z*A4.z + C4.z, 0.f) * wv.z;
        v.w = fmaxf(x.w*A4.w + C4.w, 0.f) * wv.w;
        ((float4*)gout)[f] = v;
        sum4.x += v.x; sum4.y += v.y; sum4.z += v.z; sum4.w += v.w;
        sq4.x += v.x*v.x; sq4.y += v.y*v.y; sq4.z += v.z*v.z; sq4.w += v.w*v.w;
    }
    xr4(sum4, 16); xr4(sum4, 32);
    xr4(sq4, 16);  xr4(sq4, 32);
    int l = t & 63, w = t >> 6;
    if (l < 16) { sm.p.s1[w][q] = sum4; sm.p.s2[w][q] = sq4; }
    __syncthreads();
    if (t < 16) {
        float4 a = sm.p.s1[0][t], c = sm.p.s2[0][t];
        #pragma unroll
        for (int ww = 1; ww < 4; ww++) {
            float4 x1 = sm.p.s1[ww][t], x2 = sm.p.s2[ww][t];
            a.x += x1.x; a.y += x1.y; a.z += x1.z; a.w += x1.w;
            c.x += x2.x; c.y += x2.y; c.z += x2.z; c.w += x2.w;
        }
        ((float4*)part2)[blk*32 + t]      = a;
        ((float4*)part2)[blk*32 + 16 + t] = c;
    }
    __syncthreads();
    if (t == 0) {
        __threadfence();
        s_last = (atomicAdd(ctr, 1) == NB - 1);
    }
    __syncthreads();
    if (s_last) {
        __threadfence();
        tail_reduce(part2, bn2_g, bn2_b, AC2, sm);
    }
}

// ---------- L4: bn2 apply + relu + lin(64->32) + out(32->64), wave-local LDS
__global__ __launch_bounds__(256) void k_head3(const float* __restrict__ y,
                                               const float* __restrict__ AC2,
                                               const float* __restrict__ linW,
                                               const float* __restrict__ linb,
                                               const float* __restrict__ outW,
                                               const float* __restrict__ outb,
                                               float* __restrict__ out) {
    __shared__ __align__(16) float zsh[4][64];
    __shared__ __align__(16) float hsh[4][32];
    int t = threadIdx.x;
    int d = t & 63, r = t >> 6;
    int j = d & 31, half = d >> 5;
    float A = AC2[d], C = AC2[64 + d];
    const float4* linW4 = (const float4*)linW;
    const float4* outW4 = (const float4*)outW;
    float4 lw4[8], ow4[8];
    #pragma unroll
    for (int q = 0; q < 8; q++) lw4[q] = linW4[j*16 + half*8 + q];
    #pragma unroll
    for (int q = 0; q < 8; q++) ow4[q] = outW4[d*8 + q];
    float lb = linb[j], ob = outb[d];
    const float4* zsh4 = (const float4*)zsh;
    const float4* hsh4 = (const float4*)hsh;
    for (int it = 0; it < 16; it++) {
        int row = blockIdx.x*64 + it*4 + r;
        float x = y[row*64 + d];
        float z = fmaxf(x*A + C, 0.f);
        zsh[r][d] = z;
        float p = 0.f;
        #pragma unroll
        for (int q = 0; q < 8; q++) p += dot4(zsh4[r*16 + half*8 + q], lw4[q]);
        p += __shfl_xor(p, 32);
        if (half == 0) hsh[r][j] = p + lb;
        float o = ob;
        #pragma unroll
        for (int q = 0; q < 8; q++) o += dot4(hsh4[r*8 + q], ow4[q]);
        out[row*64 + d] = o;
    }
}

extern "C" void kernel_launch(void* const* d_in, const int* in_sizes, int n_in,
                              void* d_out, int out_size, void* d_ws, size_t ws_size,
                              hipStream_t stream) {
    const float* data     = (const float*)d_in[0];
    const float* emb      = (const float*)d_in[2];
    const float* Wg       = (const float*)d_in[3];
    const float* att_i    = (const float*)d_in[4];
    const float* att_j    = (const float*)d_in[5];
    const float* att_em_i = (const float*)d_in[6];
    const float* att_em_j = (const float*)d_in[7];
    const float* bias     = (const float*)d_in[8];
    const float* bn1_g    = (const float*)d_in[9];
    const float* bn1_b    = (const float*)d_in[10];
    const float* bn2_g    = (const float*)d_in[11];
    const float* bn2_b    = (const float*)d_in[12];
    const float* linW     = (const float*)d_in[13];
    const float* linb     = (const float*)d_in[14];
    const float* outW     = (const float*)d_in[15];
    const float* outb     = (const float*)d_in[16];
    float* out = (float*)d_out;

    float* ws    = (float*)d_ws;
    int*   topk  = (int*)(ws + 512);
    float* AC1   = ws + 10752;
    float* AC2   = ws + 10880;
    float* a_i   = ws + 11264;
    float* a_j   = ws + 44032;
    float* xw    = ws + 76800;
    float* gout  = ws + 2173952;
    int*   ctr   = (int*)(ws + 4271104);
    float* part1 = ws + 4271744;
    float* part2 = ws + 4337280;

    hipMemsetAsync(ctr, 0, 64 * sizeof(int), stream);
    k_p1   <<<1024, 256, 0, stream>>>(data, emb, Wg, att_i, att_j, att_em_i, att_em_j,
                                      topk, a_i, a_j, xw);
    k_pv2  <<<NB, 256, 0, stream>>>(xw, a_i, a_j, topk, bias, bn1_g, bn1_b,
                                    gout, part1, AC1, ctr);
    k_bn2  <<<NB, 256, 0, stream>>>(gout, emb, AC1, bn2_g, bn2_b,
                                    part2, AC2, ctr + 32);
    k_head3<<<NB, 256, 0, stream>>>(gout, AC2, linW, linb, outW, outb, out);
}

// Round 14
// 184.359 us; speedup vs baseline: 2.0666x; 1.2270x over previous
//
#include <hip/hip_runtime.h>
#include <math.h>

#define Nn 512
#define Ff 64
#define Dd 64
#define Kk 20
#define ROWS 32768
#define EPSc 1e-5f
#define NEG 0.2f

// ws layout (float units):
//   512     : topk_idx[512*20] (int)
//   10752   : AC1[128] ; 10880: AC2[128]
//   11264   : a_i[32768]
//   44032   : a_j[32768]
//   76800   : xw[32768*64]
//   2173952 : gout/y [32768*64]
//   4271744 : part1[1024*128]
//   4402816 : part2[512*128]

__device__ __forceinline__ float dot4(float4 a, float4 b) {
    return a.x*b.x + a.y*b.y + a.z*b.z + a.w*b.w;
}
__device__ __forceinline__ void xr4(float4& a, int m) {
    a.x += __shfl_xor(a.x, m); a.y += __shfl_xor(a.y, m);
    a.z += __shfl_xor(a.z, m); a.w += __shfl_xor(a.w, m);
}
// XCD-aligned tiles: batch b owned by XCD b>>3. All blocks touching batch b share blk&7.
__device__ __forceinline__ int xcd_row0_64(int bb) {   // 512 blocks, 64 rows each
    int xcd = bb & 7, i = bb >> 3;
    return (xcd*8 + (i & 7))*512 + (i >> 3)*64;
}
__device__ __forceinline__ int xcd_row0_32(int bb) {   // 1024 blocks, 32 rows each
    int xcd = bb & 7, i = bb >> 3;
    return (xcd*8 + (i & 7))*512 + (i >> 3)*32;
}

// ---------- L1: topk (blocks 0..511) || xw + a_i/a_j (blocks 512..1023, XCD-aligned)
__global__ __launch_bounds__(256) void k_p1(const float* __restrict__ data,
                                            const float* __restrict__ emb,
                                            const float* __restrict__ Wg,
                                            const float* __restrict__ att_i,
                                            const float* __restrict__ att_j,
                                            const float* __restrict__ att_em_i,
                                            const float* __restrict__ att_em_j,
                                            int* __restrict__ topk,
                                            float* __restrict__ ai,
                                            float* __restrict__ aj,
                                            float* __restrict__ xw) {
    __shared__ __align__(16) float shbuf[576];
    int t = threadIdx.x, blk = blockIdx.x;
    if (blk < Nn) {
        float* wish = shbuf;
        float* sv   = shbuf + 64;
        int i = blk;
        if (t < 64) {
            float wv = emb[i*64 + t];
            float ss = wv*wv;
            #pragma unroll
            for (int s = 32; s > 0; s >>= 1) ss += __shfl_xor(ss, s);
            wish[t] = wv * (1.f / sqrtf(ss));
        }
        __syncthreads();
        int seg = t & 3, jl = t >> 2;
        const float4* wish4 = (const float4*)wish;
        float4 wn[4];
        #pragma unroll
        for (int q = 0; q < 4; q++) wn[q] = wish4[seg*4 + q];
        const float4* emb4 = (const float4*)emb;
        for (int jb = 0; jb < 8; jb++) {
            int j = jb*64 + jl;
            float p = 0.f, s2 = 0.f;
            #pragma unroll
            for (int q = 0; q < 4; q++) {
                float4 e = emb4[j*16 + seg*4 + q];
                p += dot4(e, wn[q]); s2 += dot4(e, e);
            }
            p  += __shfl_xor(p, 1);  p  += __shfl_xor(p, 2);
            s2 += __shfl_xor(s2, 1); s2 += __shfl_xor(s2, 2);
            if (seg == 0) sv[j] = p * (1.f / sqrtf(s2));
        }
        __syncthreads();
        if (t < 64) {
            float v[8];
            #pragma unroll
            for (int q = 0; q < 8; q++) v[q] = sv[q*64 + t];
            for (int k = 0; k < Kk; k++) {
                float bv = v[0]; int bi = t;
                #pragma unroll
                for (int q = 1; q < 8; q++)
                    if (v[q] > bv) { bv = v[q]; bi = q*64 + t; }
                #pragma unroll
                for (int s = 1; s < 64; s <<= 1) {
                    float ov = __shfl_xor(bv, s); int oi = __shfl_xor(bi, s);
                    if (ov > bv || (ov == bv && oi < bi)) { bv = ov; bi = oi; }
                }
                if (t == 0) topk[i*Kk + k] = bi;
                #pragma unroll
                for (int q = 0; q < 8; q++)
                    if (bi == q*64 + t) v[q] = -INFINITY;
            }
        }
    } else {
        float* sh = shbuf;
        int d = t & 63, r = t >> 6;
        const float4* wg4 = (const float4*)Wg;
        float4 w4[16];
        #pragma unroll
        for (int q = 0; q < 16; q++) w4[q] = wg4[d*16 + q];
        float atti = att_i[d], attj = att_j[d];
        float aemi = att_em_i[d], aemj = att_em_j[d];
        const float4* sh4 = (const float4*)sh;
        int row0 = xcd_row0_64(blk - Nn);            // XCD-aligned 64-row tile
        for (int it = 0; it < 16; it++) {
            int g = (row0 >> 2) + it;
            sh[t] = data[g*256 + t];                 // wave-local LDS
            float acc = 0.f;
            #pragma unroll
            for (int q = 0; q < 16; q++) acc += dot4(sh4[r*16 + q], w4[q]);
            int row = g*4 + r;
            xw[row*64 + d] = acc;
            int n = row & (Nn - 1);
            float wv = emb[n*64 + d];
            float vi = acc*atti + wv*aemi;
            float vj = acc*attj + wv*aemj;
            #pragma unroll
            for (int s = 32; s > 0; s >>= 1) { vi += __shfl_xor(vi, s); vj += __shfl_xor(vj, s); }
            if (d == 0) { ai[row] = vi; aj[row] = vj; }
        }
    }
}

// ---------- L2: alpha (LDS) + PV gather + BN1 partials.  1024 blocks x 32 rows.
__global__ __launch_bounds__(256) void k_pv(const float* __restrict__ xw,
                                            const float* __restrict__ ai,
                                            const float* __restrict__ aj,
                                            const int* __restrict__ topk,
                                            const float* __restrict__ bias,
                                            float* __restrict__ gout,
                                            float* __restrict__ part1) {
    __shared__ __align__(16) float a_lds[32][20];
    __shared__ float ssum[4][64], ssq[4][64];
    int t = threadIdx.x, blk = blockIdx.x;
    int row0 = xcd_row0_32(blk);                    // same XCD ownership as producer

    {   // alpha: 8 half-waves x 4 iters
        int hw = t >> 5, k = t & 31;
        #pragma unroll
        for (int it = 0; it < 4; it++) {
            int lr = it*8 + hw;
            int row = row0 + lr;
            int n = row & (Nn - 1);
            int base = row & ~(Nn - 1);
            float aival = ai[row];
            float v = -1e30f;
            if (k < Kk) {
                int j = topk[n*Kk + k];
                float x = aival + aj[base + j];
                v = x > 0.f ? x : NEG * x;
            }
            float m = v;
            #pragma unroll
            for (int s = 1; s <= 16; s <<= 1) m = fmaxf(m, __shfl_xor(m, s));
            float e = (k < Kk) ? __expf(v - m) : 0.f;
            float es = e;
            #pragma unroll
            for (int s = 1; s <= 16; s <<= 1) es += __shfl_xor(es, s);
            if (k < Kk) a_lds[lr][k] = e / es;
        }
    }
    __syncthreads();

    {   // PV gather + per-block partials
        int d = t & 63, r = t >> 6;
        const int4* topk4 = (const int4*)topk;
        const float4* a4 = (const float4*)&a_lds[0][0];   // row stride 5 float4
        float bias_d = bias[d];
        float lsum = 0.f, lsq = 0.f;
        #pragma unroll 4
        for (int it = 0; it < 8; it++) {
            int lr = it*4 + r;
            int row = row0 + lr;
            int n = row & (Nn - 1);
            int base = row & ~(Nn - 1);
            float acc = bias_d;
            #pragma unroll
            for (int c = 0; c < 5; c++) {
                int4   jj = topk4[n*5 + c];
                float4 aa = a4[lr*5 + c];
                acc += aa.x * xw[(base + jj.x)*64 + d];
                acc += aa.y * xw[(base + jj.y)*64 + d];
                acc += aa.z * xw[(base + jj.z)*64 + d];
                acc += aa.w * xw[(base + jj.w)*64 + d];
            }
            gout[row*64 + d] = acc;
            lsum += acc; lsq += acc*acc;
        }
        ssum[r][d] = lsum; ssq[r][d] = lsq;
        __syncthreads();
        if (t < 64) {
            float s1 = ssum[0][t] + ssum[1][t] + ssum[2][t] + ssum[3][t];
            float s2 = ssq[0][t] + ssq[1][t] + ssq[2][t] + ssq[3][t];
            part1[blk*128 + t]      = s1;   // plain stores — no fence, no atomics
            part1[blk*128 + 64 + t] = s2;
        }
    }
}

// ---------- reducer: partials[nb][128] -> AC[128]  (1 block, 1024 threads)
__global__ __launch_bounds__(1024) void k_red(const float* __restrict__ part, int nb,
                                              const float* __restrict__ g,
                                              const float* __restrict__ bta,
                                              float* __restrict__ AC) {
    __shared__ float sh1[16][64], sh2[16][64];
    int t = threadIdx.x, d = t & 63, qt = t >> 6;
    float s1 = 0.f, s2 = 0.f;
    for (int b = qt; b < nb; b += 16) {
        s1 += part[b*128 + d];
        s2 += part[b*128 + 64 + d];
    }
    sh1[qt][d] = s1; sh2[qt][d] = s2;
    __syncthreads();
    if (t < 64) {
        float t1 = 0.f, t2 = 0.f;
        #pragma unroll
        for (int i = 0; i < 16; i++) { t1 += sh1[i][t]; t2 += sh2[i][t]; }
        float mean = t1 * (1.f/ROWS);
        float var  = t2 * (1.f/ROWS) - mean*mean;
        float A = (1.f / sqrtf(var + EPSc)) * g[t];
        AC[t]      = A;
        AC[64 + t] = bta[t] - mean * A;
    }
}

// ---------- L3: bn1 apply + relu + *emb (4 float4/thread) + BN2 partials
__global__ __launch_bounds__(256) void k_bn1(float* __restrict__ gout,
                                             const float* __restrict__ emb,
                                             const float* __restrict__ AC1,
                                             float* __restrict__ part2) {
    __shared__ __align__(16) float4 s1[4][16], s2[4][16];
    int t = threadIdx.x, q = t & 15;
    float4 A4 = ((const float4*)AC1)[q];
    float4 C4 = ((const float4*)AC1)[16 + q];
    float4 sum4 = {0,0,0,0}, sq4 = {0,0,0,0};
    #pragma unroll
    for (int i = 0; i < 4; i++) {
        int f = blockIdx.x*1024 + i*256 + t;
        int row = f >> 4, n = row & (Nn - 1);
        float4 x = ((float4*)gout)[f];
        float4 wv = ((const float4*)emb)[n*16 + q];
        float4 v;
        v.x = fmaxf(x.x*A4.x + C4.x, 0.f) * wv.x;
        v.y = fmaxf(x.y*A4.y + C4.y, 0.f) * wv.y;
        v.z = fmaxf(x.z*A4.z + C4.z, 0.f) * wv.z;
        v.w = fmaxf(x.w*A4.w + C4.w, 0.f) * wv.w;
        ((float4*)gout)[f] = v;
        sum4.x += v.x; sum4.y += v.y; sum4.z += v.z; sum4.w += v.w;
        sq4.x += v.x*v.x; sq4.y += v.y*v.y; sq4.z += v.z*v.z; sq4.w += v.w*v.w;
    }
    xr4(sum4, 16); xr4(sum4, 32);
    xr4(sq4, 16);  xr4(sq4, 32);
    int l = t & 63, w = t >> 6;
    if (l < 16) { s1[w][q] = sum4; s2[w][q] = sq4; }
    __syncthreads();
    if (t < 16) {
        float4 a = s1[0][t], c = s2[0][t];
        #pragma unroll
        for (int ww = 1; ww < 4; ww++) {
            float4 x1 = s1[ww][t], x2 = s2[ww][t];
            a.x += x1.x; a.y += x1.y; a.z += x1.z; a.w += x1.w;
            c.x += x2.x; c.y += x2.y; c.z += x2.z; c.w += x2.w;
        }
        ((float4*)part2)[blockIdx.x*32 + t]      = a;
        ((float4*)part2)[blockIdx.x*32 + 16 + t] = c;
    }
}

// ---------- L4: bn2 apply + relu + lin(64->32) + out(32->64), wave-local LDS
__global__ __launch_bounds__(256) void k_head3(const float* __restrict__ y,
                                               const float* __restrict__ AC2,
                                               const float* __restrict__ linW,
                                               const float* __restrict__ linb,
                                               const float* __restrict__ outW,
                                               const float* __restrict__ outb,
                                               float* __restrict__ out) {
    __shared__ __align__(16) float zsh[4][64];
    __shared__ __align__(16) float hsh[4][32];
    int t = threadIdx.x;
    int d = t & 63, r = t >> 6;
    int j = d & 31, half = d >> 5;
    float A = AC2[d], C = AC2[64 + d];
    const float4* linW4 = (const float4*)linW;
    const float4* outW4 = (const float4*)outW;
    float4 lw4[8], ow4[8];
    #pragma unroll
    for (int q = 0; q < 8; q++) lw4[q] = linW4[j*16 + half*8 + q];
    #pragma unroll
    for (int q = 0; q < 8; q++) ow4[q] = outW4[d*8 + q];
    float lb = linb[j], ob = outb[d];
    const float4* zsh4 = (const float4*)zsh;
    const float4* hsh4 = (const float4*)hsh;
    for (int it = 0; it < 16; it++) {
        int row = blockIdx.x*64 + it*4 + r;
        float x = y[row*64 + d];
        float z = fmaxf(x*A + C, 0.f);
        zsh[r][d] = z;        // wave-local LDS — no barriers needed
        float p = 0.f;
        #pragma unroll
        for (int q = 0; q < 8; q++) p += dot4(zsh4[r*16 + half*8 + q], lw4[q]);
        p += __shfl_xor(p, 32);
        if (half == 0) hsh[r][j] = p + lb;
        float o = ob;
        #pragma unroll
        for (int q = 0; q < 8; q++) o += dot4(hsh4[r*8 + q], ow4[q]);
        out[row*64 + d] = o;
    }
}

extern "C" void kernel_launch(void* const* d_in, const int* in_sizes, int n_in,
                              void* d_out, int out_size, void* d_ws, size_t ws_size,
                              hipStream_t stream) {
    const float* data     = (const float*)d_in[0];
    const float* emb      = (const float*)d_in[2];
    const float* Wg       = (const float*)d_in[3];
    const float* att_i    = (const float*)d_in[4];
    const float* att_j    = (const float*)d_in[5];
    const float* att_em_i = (const float*)d_in[6];
    const float* att_em_j = (const float*)d_in[7];
    const float* bias     = (const float*)d_in[8];
    const float* bn1_g    = (const float*)d_in[9];
    const float* bn1_b    = (const float*)d_in[10];
    const float* bn2_g    = (const float*)d_in[11];
    const float* bn2_b    = (const float*)d_in[12];
    const float* linW     = (const float*)d_in[13];
    const float* linb     = (const float*)d_in[14];
    const float* outW     = (const float*)d_in[15];
    const float* outb     = (const float*)d_in[16];
    float* out = (float*)d_out;

    float* ws    = (float*)d_ws;
    int*   topk  = (int*)(ws + 512);
    float* AC1   = ws + 10752;
    float* AC2   = ws + 10880;
    float* a_i   = ws + 11264;
    float* a_j   = ws + 44032;
    float* xw    = ws + 76800;
    float* gout  = ws + 2173952;
    float* part1 = ws + 4271744;   // 1024*128
    float* part2 = ws + 4402816;   // 512*128

    k_p1   <<<1024, 256, 0, stream>>>(data, emb, Wg, att_i, att_j, att_em_i, att_em_j,
                                      topk, a_i, a_j, xw);
    k_pv   <<<1024, 256, 0, stream>>>(xw, a_i, a_j, topk, bias, gout, part1);
    k_red  <<<1, 1024, 0, stream>>>(part1, 1024, bn1_g, bn1_b, AC1);
    k_bn1  <<<512, 256, 0, stream>>>(gout, emb, AC1, part2);
    k_red  <<<1, 1024, 0, stream>>>(part2, 512, bn2_g, bn2_b, AC2);
    k_head3<<<512, 256, 0, stream>>>(gout, AC2, linW, linb, outW, outb, out);
}